// Round 14
// baseline (522.465 us; speedup 1.0000x reference)
//
#include <hip/hip_runtime.h>

// Problem constants: E=800000 (=3125*256), N=50000, G=16, EMB=64.
#define EMB  64
#define NREP 256   // replica lines for per-graph global atomic spreading

typedef __attribute__((ext_vector_type(8))) short bf16x8;
typedef __attribute__((ext_vector_type(4))) float f32x4;
union BF8 { bf16x8 v; short s[8]; unsigned u[4]; };

// float -> bf16 bits, round-to-nearest-even (finite inputs).
static __device__ __forceinline__ short f2bf(float f) {
    unsigned u = __float_as_uint(f);
    u += 0x7fffu + ((u >> 16) & 1u);
    return (short)(u >> 16);
}

// 2x float -> packed bf16 pair in one instruction (RNE, bit-identical to f2bf).
static __device__ __forceinline__ unsigned cvt2(float lo, float hi) {
    unsigned r;
    asm("v_cvt_pk_bf16_f32 %0, %1, %2" : "=v"(r) : "v"(lo), "v"(hi));
    return r;
}

// ---------------------------------------------------------------------------
// Prep: ecnt histogram, scalar 1-edge/thread (validated form).
// ---------------------------------------------------------------------------
__global__ __launch_bounds__(256) void prep_kernel(
    const int* __restrict__ eidx, int* __restrict__ ecnt, int E)
{
    int t = blockIdx.x * 256 + threadIdx.x;
    if (t < E) atomicAdd(&ecnt[eidx[t]], 1);
}

// ---------------------------------------------------------------------------
// Edge kernel v15 = v11's EXACT body (validated 125.7us, VALUBusy 58%,
// VGPR 84, no spill) + final_kernel absorbed as a last-block epilogue.
//
// Closed experiments on this body (do not retry):
//  * packed-f32x2 silu (R13): -18% busy cycles but +13% wall -- coupling
//    the 6 independent silu chains into 3 kills the ILP that hides trans
//    latency. Occupancy rose to 39.5% and it STILL lost: not occupancy-
//    bound, latency/ILP-bound.
//  * launch_bounds caps (R8/R12): natural pressure > cap => deterministic
//    NaN miscompile. (256,3) floor is mandatory.
//  * LDS-atomic scatter (R10): DS RMW serialization, -20%.
//  * b128 constant reads (R11): null (already merged by compiler).
// Last-block epilogue: __threadfence + ticket counter; ticket==nblocks-1
// block re-reads repsum with __hip_atomic_load(AGENT) (per-XCD L2s are not
// coherent for plain loads) and writes out. Saves final launch + duration.
// ---------------------------------------------------------------------------
__global__ __launch_bounds__(256, 3) void edge_kernel(
    const float* __restrict__ dvec, const float* __restrict__ x_edge,
    const int*   __restrict__ eidx, const int* __restrict__ batch,
    const int*   __restrict__ ecnt,
    const float* __restrict__ W1, const float* __restrict__ b1,
    const float* __restrict__ W2, const float* __restrict__ b2,
    float* __restrict__ repsum, unsigned* __restrict__ ticket,
    float* __restrict__ out, int E, int N, int nblocks)
{
    __shared__ float bins[192];   // [0,96) real, [96,192) dummy
    __shared__ f32x4 sb1N4[16], sw24[16], sw2b4[16];   // 16B constant banks
    float* sb1Nf = (float*)sb1N4;
    float* sw2f  = (float*)sw24;
    float* sw2bf = (float*)sw2b4;
    const int tid = threadIdx.x;
    const float NL2E = -1.442695040888963f;  // -log2(e)
    if (tid < 192) bins[tid] = 0.f;
    if (tid < 64) {
        float b = b1[tid], w = W2[tid];
        sb1Nf[tid] = b * NL2E;   // pre-folded exp2 bias
        sw2f[tid]  = w;
        sw2bf[tid] = w * b;      // pre-folded w2*z bias
    }
    __syncthreads();

    const int lane = tid & 63, wave = tid >> 6;
    const int col  = lane & 15, quad = lane >> 4;
    const long ebase = (long)blockIdx.x * 256 + wave * 64;

    // --- Prologue 1: scatter-metadata chain issued early, ALL lanes
    // (e depends only on col; quads 2/3 hit identical addresses).
    int nn[4];
    #pragma unroll
    for (int nt = 0; nt < 4; ++nt) {
        long e = ebase + nt * 16 + col;
        if (e >= E) e = 0;
        nn[nt] = eidx[e];
    }

    // --- Prologue 2: A fragments (W1 is 16KB, L2-hot).
    // A[m=mt*16+col][k=kt*32+quad*8+j] = W1[k][m]  (bf16 RNE)
    BF8 Af[4][2];
    #pragma unroll
    for (int mt = 0; mt < 4; ++mt)
        #pragma unroll
        for (int kt = 0; kt < 2; ++kt) {
            const float* wp = W1 + (kt * 32 + quad * 8) * 64 + mt * 16 + col;
            #pragma unroll
            for (int j = 0; j < 8; ++j) Af[mt][kt].s[j] = f2bf(wp[j * 64]);
        }

    // --- Prologue 3: resolve metadata; per-nt scatter base (branchless).
    // quads 0/1: tb = g*6 + quad*3 (real). quads 2/3: dummy slot.
    float scl[4];
    int   tb[4];
    const int dummy = 96 + (lane & 31) * 3;   // 96..189
    #pragma unroll
    for (int nt = 0; nt < 4; ++nt) {
        long e = ebase + nt * 16 + col;
        float s = __builtin_amdgcn_rcpf((float)max(ecnt[nn[nt]], 1));
        scl[nt] = (e < E) ? s : 0.f;
        int g   = batch[nn[nt]];
        tb[nt]  = (quad < 2) ? (g * 6 + quad * 3) : dummy;
    }

    const float bb2 = b2[0];

// Issue x/dvec loads for sub-tile NT into one stage register set (19 regs).
#define PIPE_ISSUE(NT, XA, XB, XC, XD, DD0, DD1, DD2)                          \
    {                                                                          \
        long e_ = ebase + (NT) * 16 + col;                                     \
        if (e_ >= E) e_ = 0;                                                   \
        const float* xp_ = x_edge + (size_t)e_ * EMB + quad * 8;               \
        XA = *(const f32x4*)(xp_);                                             \
        XB = *(const f32x4*)(xp_ + 4);                                         \
        XC = *(const f32x4*)(xp_ + 32);                                        \
        XD = *(const f32x4*)(xp_ + 36);                                        \
        DD0 = dvec[3 * e_ + 0];                                                \
        DD1 = dvec[3 * e_ + 1];                                                \
        DD2 = dvec[3 * e_ + 2];                                                \
    }

// Consume one stage; PRE (next stage's PIPE_ISSUE) sits after the B
// conversion so its load latency hides under the MFMA+silu block.
#define PIPE_BODY(NT, XA, XB, XC, XD, DD0, DD1, DD2, PRE)                      \
    {                                                                          \
        BF8 B0_, B1_;                                                          \
        B0_.u[0] = cvt2(XA.x, XA.y); B0_.u[1] = cvt2(XA.z, XA.w);              \
        B0_.u[2] = cvt2(XB.x, XB.y); B0_.u[3] = cvt2(XB.z, XB.w);              \
        B1_.u[0] = cvt2(XC.x, XC.y); B1_.u[1] = cvt2(XC.z, XC.w);              \
        B1_.u[2] = cvt2(XD.x, XD.y); B1_.u[3] = cvt2(XD.z, XD.w);              \
        float a_[6] = { DD0*DD0, DD1*DD1, DD2*DD2, DD0*DD1, DD0*DD2, DD1*DD2 };\
        float aN_[6];                                                          \
        _Pragma("unroll")                                                      \
        for (int c = 0; c < 6; ++c) aN_[c] = a_[c] * NL2E;                     \
        PRE                                                                    \
        float acc_[6] = { 0.f, 0.f, 0.f, 0.f, 0.f, 0.f };                      \
        _Pragma("unroll")                                                      \
        for (int mt = 0; mt < 4; ++mt) {                                       \
            f32x4 D_ = { 0.f, 0.f, 0.f, 0.f };                                 \
            D_ = __builtin_amdgcn_mfma_f32_16x16x32_bf16(Af[mt][0].v, B0_.v, D_, 0, 0, 0); \
            D_ = __builtin_amdgcn_mfma_f32_16x16x32_bf16(Af[mt][1].v, B1_.v, D_, 0, 0, 0); \
            f32x4 bN4_ = sb1N4[mt * 4 + quad];                                 \
            f32x4 w24_ = sw24 [mt * 4 + quad];                                 \
            f32x4 wb4_ = sw2b4[mt * 4 + quad];                                 \
            _Pragma("unroll")                                                  \
            for (int r = 0; r < 4; ++r) {                                      \
                float y_  = D_[r];                                             \
                float bN_ = bN4_[r];                                           \
                float wy_ = w24_[r] * y_;                                      \
                float wb_ = wb4_[r];                                           \
                _Pragma("unroll")                                              \
                for (int c = 0; c < 6; ++c) {                                  \
                    float arg_ = fmaf(aN_[c], y_, bN_);                        \
                    float ex_  = __builtin_amdgcn_exp2f(arg_);                 \
                    float rr_  = __builtin_amdgcn_rcpf(1.0f + ex_);            \
                    float w2z_ = fmaf(a_[c], wy_, wb_);                        \
                    acc_[c]    = fmaf(w2z_, rr_, acc_[c]);                     \
                }                                                              \
            }                                                                  \
        }                                                                      \
        _Pragma("unroll")                                                      \
        for (int c = 0; c < 6; ++c) {                                          \
            acc_[c] += __shfl_xor(acc_[c], 16, 64);                            \
            acc_[c] += __shfl_xor(acc_[c], 32, 64);                            \
        }                                                                      \
        const int c0_ = (quad & 1) * 3;                                        \
        _Pragma("unroll")                                                      \
        for (int j = 0; j < 3; ++j)                                            \
            atomicAdd(&bins[tb[NT] + j], (acc_[c0_ + j] + bb2) * scl[NT]);     \
    }

    f32x4 Pxa, Pxb, Pxc, Pxd; float Pd0, Pd1, Pd2;
    f32x4 Qxa, Qxb, Qxc, Qxd; float Qd0, Qd1, Qd2;

    PIPE_ISSUE(0, Pxa, Pxb, Pxc, Pxd, Pd0, Pd1, Pd2)
    PIPE_BODY(0, Pxa, Pxb, Pxc, Pxd, Pd0, Pd1, Pd2,
              PIPE_ISSUE(1, Qxa, Qxb, Qxc, Qxd, Qd0, Qd1, Qd2))
    PIPE_BODY(1, Qxa, Qxb, Qxc, Qxd, Qd0, Qd1, Qd2,
              PIPE_ISSUE(2, Pxa, Pxb, Pxc, Pxd, Pd0, Pd1, Pd2))
    PIPE_BODY(2, Pxa, Pxb, Pxc, Pxd, Pd0, Pd1, Pd2,
              PIPE_ISSUE(3, Qxa, Qxb, Qxc, Qxd, Qd0, Qd1, Qd2))
    PIPE_BODY(3, Qxa, Qxb, Qxc, Qxd, Qd0, Qd1, Qd2, )

#undef PIPE_ISSUE
#undef PIPE_BODY

    __syncthreads();
    if (tid < 96) {
        int rep = blockIdx.x & (NREP - 1);
        atomicAdd(repsum + (size_t)rep * 96 + tid, bins[tid]);
    }

    // --- Last-block epilogue: replaces the separate final_kernel launch.
    __shared__ unsigned isLast;
    if (tid == 0) {
        __threadfence();                         // order repsum flush first
        unsigned done = atomicAdd(ticket, 1u);
        isLast = (done == (unsigned)(nblocks - 1)) ? 1u : 0u;
    }
    __syncthreads();
    if (isLast) {
        __threadfence();                         // acquire side
        __shared__ float sh[96];
        __shared__ int gs[17];
        if (tid < 17) {
            // lower_bound: first i with batch[i] >= tid (batch sorted, 16 graphs)
            int lo = 0, hi = N;
            while (lo < hi) {
                int mid = (lo + hi) >> 1;
                if (batch[mid] < tid) lo = mid + 1; else hi = mid;
            }
            gs[tid] = lo;
        }
        if (tid < 96) {
            float s = 0.f;
            #pragma unroll 8
            for (int r = 0; r < NREP; ++r)
                s += __hip_atomic_load(repsum + (size_t)r * 96 + tid,
                                       __ATOMIC_RELAXED, __HIP_MEMORY_SCOPE_AGENT);
            sh[tid] = s;
        }
        __syncthreads();
        if (tid < 16) {
            int gN = gs[tid + 1] - gs[tid];
            float inv = 1.0f / fmaxf((float)gN, 1.0f);
            float m0 = sh[tid * 6 + 0] * inv;
            float m1 = sh[tid * 6 + 1] * inv;
            float m2 = sh[tid * 6 + 2] * inv;
            float m3 = sh[tid * 6 + 3] * inv;
            float m4 = sh[tid * 6 + 4] * inv;
            float m5 = sh[tid * 6 + 5] * inv;
            float* p = out + tid * 9;
            p[0] = m0; p[1] = m3; p[2] = m4;
            p[3] = m3; p[4] = m1; p[5] = m5;
            p[6] = m4; p[7] = m5; p[8] = m2;
        }
    }
}

// ---------------------------------------------------------------------------
extern "C" void kernel_launch(void* const* d_in, const int* in_sizes, int n_in,
                              void* d_out, int out_size, void* d_ws, size_t ws_size,
                              hipStream_t stream) {
    const float* dvec   = (const float*)d_in[0];   // [E,3]
    const float* x_edge = (const float*)d_in[1];   // [E,64]
    const int*   eidx   = (const int*)d_in[2];     // [E]
    const int*   batch  = (const int*)d_in[3];     // [N] sorted
    const float* W1     = (const float*)d_in[6];   // [64,64] (in,out)
    const float* b1     = (const float*)d_in[7];   // [64]
    const float* W2     = (const float*)d_in[8];   // [64,1]
    const float* b2     = (const float*)d_in[9];   // [1]

    int E = in_sizes[0] / 3;   // 800000
    int N = in_sizes[3];       // 50000

    // ws: ecnt[N] int | repsum[NREP*96] float | ticket[1] uint (contiguous)
    int*      ecnt   = (int*)d_ws;
    float*    repsum = (float*)(ecnt + N);
    unsigned* ticket = (unsigned*)(repsum + (size_t)NREP * 96);

    hipMemsetAsync(d_ws, 0, ((size_t)N + (size_t)NREP * 96 + 1) * 4, stream);

    int blocks = (E + 255) / 256;   // 3125
    prep_kernel<<<blocks, 256, 0, stream>>>(eidx, ecnt, E);
    edge_kernel<<<blocks, 256, 0, stream>>>(dvec, x_edge, eidx, batch, ecnt,
                                            W1, b1, W2, b2, repsum, ticket,
                                            (float*)d_out, E, N, blocks);
}